// Round 9
// baseline (714.030 us; speedup 1.0000x reference)
//
#include <hip/hip_runtime.h>
#include <math.h>

#define SEQ 192
#define NTOK 24576      // 128*192
#define EPS 1e-5f

typedef __bf16 bf16x8 __attribute__((ext_vector_type(8)));
typedef __bf16 bf16x4 __attribute__((ext_vector_type(4)));
typedef float  f32x4  __attribute__((ext_vector_type(4)));

__device__ __forceinline__ void load_lds16(const __bf16* g, __bf16* l) {
    __builtin_amdgcn_global_load_lds(
        (const __attribute__((address_space(1))) uint32_t*)g,
        (__attribute__((address_space(3))) uint32_t*)l, 16, 0, 0);
}

// tanh-form GELU via sigmoid: x*sigmoid(1.5958*(x+0.044715 x^3))
__device__ __forceinline__ float gelu_f(float x) {
    float z = 1.5957691216057308f * x * fmaf(0.044715f, x*x, 1.f);
    float e = __expf(-z);
    return x * __builtin_amdgcn_rcpf(1.f + e);
}

// ---------------- fused: weight f32->bf16 convert + src prep (one dispatch) ----------------
__global__ __launch_bounds__(256) void cvtprep_k(
    const float* __restrict__ s0, const float* __restrict__ s1, const float* __restrict__ s2,
    const float* __restrict__ s3, const float* __restrict__ s4, const float* __restrict__ s5,
    __bf16* __restrict__ dst,
    const float* __restrict__ src, __bf16* __restrict__ srcb, __bf16* __restrict__ srcnb)
{
    if (blockIdx.x < 4864) {
        int i = blockIdx.x * 256 + threadIdx.x;   // f32x4 units
        int f = i * 4;
        const float* s; int off;
        if      (f <  524288) { s = s0; off = 0;       }
        else if (f <  786432) { s = s1; off = 524288;  }
        else if (f < 1835008) { s = s2; off = 786432;  }
        else if (f < 2883584) { s = s3; off = 1835008; }
        else if (f < 3932160) { s = s4; off = 2883584; }
        else                  { s = s5; off = 3932160; }
        f32x4 v = *(const f32x4*)&s[f - off];
        bf16x4 o;
        o[0]=(__bf16)v[0]; o[1]=(__bf16)v[1]; o[2]=(__bf16)v[2]; o[3]=(__bf16)v[3];
        ((bf16x4*)dst)[i] = o;
    } else {
        int blk = blockIdx.x - 4864;              // 6144 blocks
        int w = threadIdx.x >> 6, lane = threadIdx.x & 63;
        size_t token = blk * 4 + w;
        const float* p = src + token * 512 + lane * 8;
        f32x4 a0 = *(const f32x4*)p;
        f32x4 a1 = *(const f32x4*)(p + 4);
        float s = a0[0]*a0[0]+a0[1]*a0[1]+a0[2]*a0[2]+a0[3]*a0[3]
                + a1[0]*a1[0]+a1[1]*a1[1]+a1[2]*a1[2]+a1[3]*a1[3];
#pragma unroll
        for (int off = 32; off; off >>= 1) s += __shfl_xor(s, off);
        float rs = rsqrtf(s);
        bf16x8 vb, vn;
#pragma unroll
        for (int q = 0; q < 4; q++) {
            vb[q]   = (__bf16)a0[q];      vn[q]   = (__bf16)(a0[q]*rs);
            vb[q+4] = (__bf16)a1[q];      vn[q+4] = (__bf16)(a1[q]*rs);
        }
        *(bf16x8*)&srcb[token*512 + lane*8]  = vb;
        *(bf16x8*)&srcnb[token*512 + lane*8] = vn;
    }
}

// ---------------- bf16 MFMA NT GEMM, BK=64, XOR-swizzled LDS, bf16 out ----------------
// 128x128 tile; m-tiles XCD-grouped.
// DUALM: rows >= M1 come from a second (A,B,C,bias) set (same N).
// NSPLIT: n-tiles >= M1 columns come from a second (A,B,C,bias) set with width N2.
template<bool GELU, bool DUALM, bool NSPLIT>
__global__ __launch_bounds__(256) void gemm_k(
    const __bf16* __restrict__ A, const __bf16* __restrict__ B, __bf16* __restrict__ C,
    int N, int K, const float* __restrict__ bias,
    const __bf16* __restrict__ A2, const __bf16* __restrict__ B2, __bf16* __restrict__ C2,
    const float* __restrict__ bias2, int M1, int N2)
{
    __shared__ __bf16 As[8192];   // [128][64], seg XOR-swizzled
    __shared__ __bf16 Bs[8192];
    const int tid = threadIdx.x, lane = tid & 63, w = tid >> 6;
    const int wr = w >> 1, wc = w & 1;
    const int b = blockIdx.y * gridDim.x + blockIdx.x;
    const int xcd = b & 7, bi = b >> 3;
    const int ypx = gridDim.y >> 3;
    int m0 = (xcd * ypx + bi / gridDim.x) * 128;
    int n0 = (bi % gridDim.x) * 128;
    if (DUALM && m0 >= M1)  { A = A2; B = B2; C = C2; bias = bias2; m0 -= M1; }
    if (NSPLIT && n0 >= M1) { A = A2; B = B2; C = C2; bias = bias2; n0 -= M1; N = N2; }
    const int fr = lane & 15, fq = lane >> 4;
    const int grow = 8*w + (lane >> 3);
    const int gcol = ((lane & 7) ^ (lane >> 3)) * 8;
    const __bf16* gB = B + (size_t)(n0 + grow) * K + gcol;
    const __bf16* gA = A + (size_t)(m0 + grow) * K + gcol;
    __bf16* ldsA = As + 8*w*64 + lane*8;
    __bf16* ldsB = Bs + 8*w*64 + lane*8;

    f32x4 acc[4][4];
#pragma unroll
    for (int i = 0; i < 4; i++)
#pragma unroll
        for (int j = 0; j < 4; j++) acc[i][j] = (f32x4){0.f,0.f,0.f,0.f};

    for (int k0 = 0; k0 < K; k0 += 64) {
#pragma unroll
        for (int i = 0; i < 4; i++)
            load_lds16(gA + k0 + (size_t)(32*i)*K, ldsA + i*2048);
#pragma unroll
        for (int i = 0; i < 4; i++)
            load_lds16(gB + k0 + (size_t)(32*i)*K, ldsB + i*2048);
        __syncthreads();
#pragma unroll
        for (int kk = 0; kk < 2; kk++) {
            bf16x8 af[4], bfv[4];
#pragma unroll
            for (int i = 0; i < 4; i++)
                af[i] = *(bf16x8*)&As[(wr*64 + i*16 + fr)*64 + (((kk*4+fq) ^ (fr&7))*8)];
#pragma unroll
            for (int j = 0; j < 4; j++)
                bfv[j] = *(bf16x8*)&Bs[(wc*64 + j*16 + fr)*64 + (((kk*4+fq) ^ (fr&7))*8)];
#pragma unroll
            for (int i = 0; i < 4; i++)
#pragma unroll
                for (int j = 0; j < 4; j++)
                    acc[i][j] = __builtin_amdgcn_mfma_f32_16x16x32_bf16(af[i], bfv[j], acc[i][j], 0, 0, 0);
        }
        __syncthreads();
    }
    const int r4 = lane >> 4, cc = lane & 15;
#pragma unroll
    for (int i = 0; i < 4; i++) {
#pragma unroll
        for (int r = 0; r < 4; r++) {
            int m = m0 + wr*64 + i*16 + r4*4 + r;
#pragma unroll
            for (int j = 0; j < 4; j++) {
                int n = n0 + wc*64 + j*16 + cc;
                float v = acc[i][j][r] + bias[n];
                if (GELU) v = gelu_f(v);
                C[(size_t)m * N + n] = (__bf16)v;
            }
        }
    }
}

// ---------------- fold BN affine into W1 (both FFNs in one dispatch) ----------------
__global__ __launch_bounds__(256) void w1scale_k(
    __bf16* __restrict__ w1a, __bf16* __restrict__ w1b, const float* __restrict__ coef01,
    const float* __restrict__ b1in, const float* __restrict__ b2in,
    float* __restrict__ b1out, float* __restrict__ b2out)
{
    const int half = blockIdx.x >> 9;
    __bf16* wbase = half ? w1b : w1a;
    const float* coef = coef01 + half*1024;
    const float* bin  = half ? b2in  : b1in;
    float* bout       = half ? b2out : b1out;
    const int wv = threadIdx.x >> 6, lane = threadIdx.x & 63;
    const int n = (blockIdx.x & 511) * 4 + wv;
    __bf16* p = wbase + (size_t)n * 512 + lane * 8;
    bf16x8 v = *(bf16x8*)p;
    f32x4 sc0 = *(const f32x4*)(coef + lane*8);
    f32x4 sc1 = *(const f32x4*)(coef + lane*8 + 4);
    f32x4 sh0 = *(const f32x4*)(coef + 512 + lane*8);
    f32x4 sh1 = *(const f32x4*)(coef + 512 + lane*8 + 4);
    float dot = 0.f;
    bf16x8 o;
#pragma unroll
    for (int q = 0; q < 4; q++) {
        float w0 = (float)v[q], w1 = (float)v[q+4];
        o[q]   = (__bf16)(w0 * sc0[q]);
        o[q+4] = (__bf16)(w1 * sc1[q]);
        dot = fmaf(w0, sh0[q], dot);
        dot = fmaf(w1, sh1[q], dot);
    }
    *(bf16x8*)p = o;
#pragma unroll
    for (int off = 32; off; off >>= 1) dot += __shfl_xor(dot, off);
    if (lane == 0) bout[n] = bin[n] + dot;
}

// ---------------- dual-source W2 GEMM, double-buffered (stage-ahead 2-phase) ----------------
// out = H1*B1^T + H2*B2^T + b1 + b2 + resid ; 64x128 tile, 768 blocks, XCD-grouped.
__global__ __launch_bounds__(256) void gemm2_k(
    const __bf16* __restrict__ A1, const __bf16* __restrict__ A2,
    const __bf16* __restrict__ B1, const __bf16* __restrict__ B2,
    float* __restrict__ C, const float* __restrict__ b1, const float* __restrict__ b2,
    const float* __restrict__ resid, float* __restrict__ st)
{
    __shared__ __bf16 As[2][4096];   // 64 x 64 x 2buf
    __shared__ __bf16 Bs[2][8192];   // 128 x 64 x 2buf
    const int tid = threadIdx.x, lane = tid & 63, w = tid >> 6;
    const int wr = w >> 1, wc = w & 1;
    const int vb = blockIdx.x;                  // 768 = 8 xcd * 24 m * 4 n
    const int xcd = vb & 7, k2 = vb >> 3;
    const int m0 = (xcd*24 + (k2 >> 2)) * 64;
    const int n0 = (k2 & 3) * 128;
    const int fr = lane & 15, fq = lane >> 4;
    const int grow = 8*w + (lane >> 3);
    const int gcol = ((lane & 7) ^ (lane >> 3)) * 8;
    const int K = 2048;
    const int ldsoff = 8*w*64 + lane*8;
    const __bf16* gA1 = A1 + (size_t)(m0 + grow) * K + gcol;
    const __bf16* gA2 = A2 + (size_t)(m0 + grow) * K + gcol;
    const __bf16* gB1 = B1 + (size_t)(n0 + grow) * K + gcol;
    const __bf16* gB2 = B2 + (size_t)(n0 + grow) * K + gcol;

#define G2_STAGE(pb, it_) do {                                              \
        int half_ = (it_) >> 5, k0_ = ((it_) & 31) * 64;                    \
        const __bf16* ga_ = (half_ ? gA2 : gA1) + k0_;                      \
        const __bf16* gb_ = (half_ ? gB2 : gB1) + k0_;                      \
        load_lds16(ga_,                  &As[pb][ldsoff]);                  \
        load_lds16(ga_ + (size_t)32*K,   &As[pb][ldsoff + 2048]);           \
        load_lds16(gb_,                  &Bs[pb][ldsoff]);                  \
        load_lds16(gb_ + (size_t)32*K,   &Bs[pb][ldsoff + 2048]);           \
        load_lds16(gb_ + (size_t)64*K,   &Bs[pb][ldsoff + 4096]);           \
        load_lds16(gb_ + (size_t)96*K,   &Bs[pb][ldsoff + 6144]);           \
    } while (0)

    f32x4 acc[2][4];
#pragma unroll
    for (int i = 0; i < 2; i++)
#pragma unroll
        for (int j = 0; j < 4; j++) acc[i][j] = (f32x4){0.f,0.f,0.f,0.f};

    G2_STAGE(0, 0);
    asm volatile("s_waitcnt vmcnt(0)" ::: "memory");
    __syncthreads();
    for (int it = 0; it < 64; ++it) {
        const int cur = it & 1;
        if (it + 1 < 64) G2_STAGE(cur ^ 1, it + 1);   // loads for next tile fly over compute
#pragma unroll
        for (int kk = 0; kk < 2; kk++) {
            bf16x8 af[2], bfv[4];
#pragma unroll
            for (int i = 0; i < 2; i++)
                af[i] = *(bf16x8*)&As[cur][(wr*32 + i*16 + fr)*64 + (((kk*4+fq) ^ (fr&7))*8)];
#pragma unroll
            for (int j = 0; j < 4; j++)
                bfv[j] = *(bf16x8*)&Bs[cur][(wc*64 + j*16 + fr)*64 + (((kk*4+fq) ^ (fr&7))*8)];
#pragma unroll
            for (int i = 0; i < 2; i++)
#pragma unroll
                for (int j = 0; j < 4; j++)
                    acc[i][j] = __builtin_amdgcn_mfma_f32_16x16x32_bf16(af[i], bfv[j], acc[i][j], 0, 0, 0);
        }
        asm volatile("s_waitcnt vmcnt(0)" ::: "memory");
        __syncthreads();
    }
#undef G2_STAGE

    const int r4 = lane >> 4, cc = lane & 15;
    float cs[4] = {0,0,0,0}, cq[4] = {0,0,0,0};
#pragma unroll
    for (int i = 0; i < 2; i++) {
#pragma unroll
        for (int r = 0; r < 4; r++) {
            int m = m0 + wr*32 + i*16 + r4*4 + r;
#pragma unroll
            for (int j = 0; j < 4; j++) {
                int n = n0 + wc*64 + j*16 + cc;
                size_t idx = (size_t)m * 512 + n;
                float v = acc[i][j][r] + b1[n] + b2[n] + resid[idx];
                C[idx] = v;
                cs[j] += v; cq[j] = fmaf(v, v, cq[j]);
            }
        }
    }
#pragma unroll
    for (int j = 0; j < 4; j++) {
        cs[j] += __shfl_xor(cs[j], 16); cs[j] += __shfl_xor(cs[j], 32);
        cq[j] += __shfl_xor(cq[j], 16); cq[j] += __shfl_xor(cq[j], 32);
    }
    if (r4 == 0) {
#pragma unroll
        for (int j = 0; j < 4; j++) {
            int n = n0 + wc*64 + j*16 + cc;
            atomicAdd(&st[n], cs[j]);
            atomicAdd(&st[512 + n], cq[j]);
        }
    }
}

// ---------------- hidden-axis attention body (T14 V-hoist + fused BN stats) ----------------
// BN channel of output elem (t, dloc): c = flat%512 = (t&7)*64 + dloc = ((fq*4+reg)&7)*64
// + nt*16 + fr — independent of mt/w/nh/bn (verified against bn_stats1 flat semantics).
__device__ __forceinline__ void hidden_attn_body(
    const __bf16* __restrict__ QKb, const __bf16* __restrict__ Vb, __bf16* __restrict__ OHb,
    float* __restrict__ stg, __bf16* smem, int bn, int nh)
{
    __bf16* Qt = smem;             // 64 x 200 (phase 1)  [e][t]
    __bf16* Kt = smem + 12800;     // 64 x 200            [f][t]
    __bf16* Ps = smem;             // 64 x 72  (phase 2)  [e][f]
    __bf16* Vs = smem + 4608;      // 192 x 72            [t][f]
    float* stLds = (float*)(smem + 27648);   // 1024 f32 stats scratch (past all phases)
    const int tid = threadIdx.x, lane = tid & 63, w = tid >> 6;
    const int fr = lane & 15, fq = lane >> 4;
    const size_t rowbase = (size_t)bn * SEQ;

    // transpose-stage q^T,k^T: per task one column-of-8 (8 coalesced reads + 1 b128 write)
#pragma unroll
    for (int it = 0; it < 12; it++) {
        int tk = tid + (it % 6) * 256;          // 0..1535
        int j = tk & 63, tg = tk >> 6;          // tg 0..23
        const __bf16* gsrc = QKb + (rowbase + tg*8)*1024 + nh*64 + j + (it >= 6 ? 512 : 0);
        bf16x8 v;
#pragma unroll
        for (int u = 0; u < 8; u++) v[u] = gsrc[(size_t)u*1024];
        __bf16* dst = (it >= 6 ? Kt : Qt) + j*200 + tg*8;
        *(bf16x8*)dst = v;
    }
    // T14 async-STAGE: issue V loads NOW (land under QK^T+softmax); write to LDS late.
    bf16x8 vreg[6];
#pragma unroll
    for (int it = 0; it < 6; it++) {
        int i = tid + it*256;
        int t = i >> 3, s = i & 7;
        vreg[it] = *(const bf16x8*)&Vb[(rowbase+t)*512 + nh*64 + s*8];
    }
    __syncthreads();

    f32x4 acc[4];
#pragma unroll
    for (int i = 0; i < 4; i++) acc[i] = (f32x4){0.f,0.f,0.f,0.f};
#pragma unroll
    for (int kc = 0; kc < 6; kc++) {
        bf16x8 a = *(bf16x8*)&Qt[(w*16 + fr)*200 + kc*32 + fq*8];
#pragma unroll
        for (int nt = 0; nt < 4; nt++) {
            bf16x8 b = *(bf16x8*)&Kt[(nt*16 + fr)*200 + kc*32 + fq*8];
            acc[nt] = __builtin_amdgcn_mfma_f32_16x16x32_bf16(a, b, acc[nt], 0, 0, 0);
        }
    }
    const float sc = 13.856406460551018f;   // sqrt(192)
    float pn[4][4];
#pragma unroll
    for (int reg = 0; reg < 4; reg++) {
        float m = -1e30f;
#pragma unroll
        for (int nt = 0; nt < 4; nt++) { acc[nt][reg] *= sc; m = fmaxf(m, acc[nt][reg]); }
#pragma unroll
        for (int off = 1; off < 16; off <<= 1) m = fmaxf(m, __shfl_xor(m, off));
        float l = 0.f;
#pragma unroll
        for (int nt = 0; nt < 4; nt++) { pn[nt][reg] = __expf(acc[nt][reg] - m); l += pn[nt][reg]; }
#pragma unroll
        for (int off = 1; off < 16; off <<= 1) l += __shfl_xor(l, off);
        float inv = 1.f / l;
#pragma unroll
        for (int nt = 0; nt < 4; nt++) pn[nt][reg] *= inv;
    }
    __syncthreads();                                   // Qt/Kt dead
#pragma unroll
    for (int nt = 0; nt < 4; nt++)
#pragma unroll
        for (int reg = 0; reg < 4; reg++)
            Ps[(w*16 + fq*4 + reg)*72 + nt*16 + fr] = (__bf16)pn[nt][reg];
#pragma unroll
    for (int it = 0; it < 6; it++) {                   // V regs -> LDS (loads long landed)
        int i = tid + it*256;
        int t = i >> 3, s = i & 7;
        *(bf16x8*)&Vs[t*72 + s*8] = vreg[it];
    }
    ((f32x4*)stLds)[tid] = (f32x4){0.f,0.f,0.f,0.f};   // zero stats scratch
    __syncthreads();

    f32x4 o[3][4];
#pragma unroll
    for (int i = 0; i < 3; i++)
#pragma unroll
        for (int j = 0; j < 4; j++) o[i][j] = (f32x4){0.f,0.f,0.f,0.f};
#pragma unroll
    for (int kc = 0; kc < 2; kc++) {
        bf16x8 av[3];
#pragma unroll
        for (int mt = 0; mt < 3; mt++)
            av[mt] = *(bf16x8*)&Vs[(48*w + mt*16 + fr)*72 + kc*32 + fq*8];
#pragma unroll
        for (int nt = 0; nt < 4; nt++) {
            bf16x8 b = *(bf16x8*)&Ps[(nt*16 + fr)*72 + kc*32 + fq*8];
#pragma unroll
            for (int mt = 0; mt < 3; mt++)
                o[mt][nt] = __builtin_amdgcn_mfma_f32_16x16x32_bf16(av[mt], b, o[mt][nt], 0, 0, 0);
        }
    }
    __bf16* obase = OHb + ((size_t)(bn*8 + nh)) * SEQ * 64;
    float cs[4][4], cq[4][4];
#pragma unroll
    for (int r = 0; r < 4; r++)
#pragma unroll
        for (int j = 0; j < 4; j++) { cs[r][j] = 0.f; cq[r][j] = 0.f; }
#pragma unroll
    for (int mt = 0; mt < 3; mt++)
#pragma unroll
        for (int reg = 0; reg < 4; reg++) {
            int t = 48*w + mt*16 + fq*4 + reg;
#pragma unroll
            for (int nt = 0; nt < 4; nt++) {
                __bf16 ob = (__bf16)o[mt][nt][reg];
                obase[(size_t)t*64 + nt*16 + fr] = ob;
                float vf = (float)ob;
                cs[reg][nt] += vf; cq[reg][nt] = fmaf(vf, vf, cq[reg][nt]);
            }
        }
#pragma unroll
    for (int reg = 0; reg < 4; reg++)
#pragma unroll
        for (int nt = 0; nt < 4; nt++) {
            cs[reg][nt] += __shfl_xor(cs[reg][nt], 32);   // fq ^ 2 -> same channel
            cq[reg][nt] += __shfl_xor(cq[reg][nt], 32);
        }
    if (fq < 2) {
#pragma unroll
        for (int reg = 0; reg < 4; reg++)
#pragma unroll
            for (int nt = 0; nt < 4; nt++) {
                int c = ((fq*4 + reg) & 7)*64 + nt*16 + fr;
                atomicAdd(&stLds[c], cs[reg][nt]);
                atomicAdd(&stLds[512 + c], cq[reg][nt]);
            }
    }
    __syncthreads();
#pragma unroll
    for (int j = 0; j < 4; j++)
        atomicAdd(&stg[tid*4 + j], stLds[tid*4 + j]);
}

// ---------------- token-axis attention body (in-LDS decay scan, batched; T14; fused BN stats) --
__device__ __forceinline__ void token_attn_body(
    const __bf16* __restrict__ QKb, const __bf16* __restrict__ Vb, __bf16* __restrict__ OT,
    const float* __restrict__ alpha, float* __restrict__ stg, __bf16* smem, int bn, int nh)
{
    __bf16* Qs = smem;              // 192 x 72 (phase A) [e][d]
    __bf16* Ks = smem + 13824;      // 192 x 72           [f][d]
    __bf16* Vt = smem;              // 64 x 200 (phase B) [d][f]
    __bf16* Pw = smem + 12800;      // 4 waves x (48 x 72)
    float* stLds = (float*)(smem + 27648);   // 1024 f32 stats scratch (past Ks end)
    const int tid = threadIdx.x, lane = tid & 63, w = tid >> 6;
    const int fr = lane & 15, fq = lane >> 4;
    const size_t rowbase = (size_t)bn * SEQ;

    for (int i = tid; i < 1536; i += 256) {
        int t = i >> 3, s = i & 7;
        const __bf16* g = QKb + (rowbase + t)*1024 + nh*64;
        *(bf16x8*)&Qs[t*72 + s*8] = *(const bf16x8*)&g[s*8];
        *(bf16x8*)&Ks[t*72 + s*8] = *(const bf16x8*)&g[512 + s*8];
    }
    // T14 async-STAGE: issue the V^T transpose-gather NOW — lands under scan + QK^T + softmax.
    bf16x8 vreg[6];
#pragma unroll
    for (int it = 0; it < 6; it++) {
        int tk = tid + it * 256;                // 0..1535
        int d = tk & 63, tg = tk >> 6;
        const __bf16* gsrc = Vb + (rowbase + tg*8)*512 + nh*64 + d;
#pragma unroll
        for (int u = 0; u < 8; u++) vreg[it][u] = gsrc[(size_t)u*512];
    }
    __syncthreads();

    // in-LDS decay scan over t, 16-wide batched (reads issued together so LDS latency
    // overlaps 16-deep; per-element arithmetic order identical to the scalar loop).
    if (tid < 128) {
        const int d = tid & 63;
        __bf16* col = (tid < 64) ? (Qs + d) : (Ks + d);
        const float av = 1.f / (1.f + __expf(-alpha[d]));
        const float r = 1.f - av;
        float P = 0.f, pw = 1.f;
        for (int t0 = 0; t0 < SEQ; t0 += 16) {
            float x[16];
#pragma unroll
            for (int u = 0; u < 16; u++) x[u] = (float)col[(t0+u)*72];
#pragma unroll
            for (int u = 0; u < 16; u++) { P = fmaf(pw, x[u], P); x[u] = P; pw *= r; }
#pragma unroll
            for (int u = 0; u < 16; u++) col[(t0+u)*72] = (__bf16)x[u];
        }
        float f = av;
        for (int t0 = SEQ-16; t0 >= 0; t0 -= 16) {
            float x[16];
#pragma unroll
            for (int u = 0; u < 16; u++) x[u] = (float)col[(t0+u)*72];
#pragma unroll
            for (int u = 15; u >= 0; u--) { x[u] *= f; f *= r; }
#pragma unroll
            for (int u = 0; u < 16; u++) col[(t0+u)*72] = (__bf16)x[u];
        }
    }
    __syncthreads();

    f32x4 S[3][12];
#pragma unroll
    for (int i = 0; i < 3; i++)
#pragma unroll
        for (int j = 0; j < 12; j++) S[i][j] = (f32x4){0.f,0.f,0.f,0.f};
#pragma unroll
    for (int kc = 0; kc < 2; kc++) {
        bf16x8 aq[3];
#pragma unroll
        for (int mt = 0; mt < 3; mt++)
            aq[mt] = *(bf16x8*)&Qs[(48*w + mt*16 + fr)*72 + kc*32 + fq*8];
#pragma unroll
        for (int nt = 0; nt < 12; nt++) {
            bf16x8 b = *(bf16x8*)&Ks[(nt*16 + fr)*72 + kc*32 + fq*8];
#pragma unroll
            for (int mt = 0; mt < 3; mt++)
                S[mt][nt] = __builtin_amdgcn_mfma_f32_16x16x32_bf16(aq[mt], b, S[mt][nt], 0, 0, 0);
        }
    }
#pragma unroll
    for (int mt = 0; mt < 3; mt++)
#pragma unroll
        for (int reg = 0; reg < 4; reg++) {
            float m = -1e30f;
#pragma unroll
            for (int nt = 0; nt < 12; nt++) { S[mt][nt][reg] *= 8.f; m = fmaxf(m, S[mt][nt][reg]); }
#pragma unroll
            for (int off = 1; off < 16; off <<= 1) m = fmaxf(m, __shfl_xor(m, off));
            float l = 0.f;
#pragma unroll
            for (int nt = 0; nt < 12; nt++) { S[mt][nt][reg] = __expf(S[mt][nt][reg] - m); l += S[mt][nt][reg]; }
#pragma unroll
            for (int off = 1; off < 16; off <<= 1) l += __shfl_xor(l, off);
            float inv = 1.f / l;
#pragma unroll
            for (int nt = 0; nt < 12; nt++) S[mt][nt][reg] *= inv;
        }
    __syncthreads();                                   // Qs/Ks dead
    // V^T regs -> LDS (gather loads issued in phase A have long landed)
#pragma unroll
    for (int it = 0; it < 6; it++) {
        int tk = tid + it * 256;
        int d = tk & 63, tg = tk >> 6;
        *(bf16x8*)&Vt[d*200 + tg*8] = vreg[it];
    }
    ((f32x4*)stLds)[tid] = (f32x4){0.f,0.f,0.f,0.f};   // zero stats scratch
    __syncthreads();

    f32x4 O[3][4];
#pragma unroll
    for (int i = 0; i < 3; i++)
#pragma unroll
        for (int j = 0; j < 4; j++) O[i][j] = (f32x4){0.f,0.f,0.f,0.f};
    __bf16* myP = Pw + w*3456;
#pragma unroll
    for (int fc = 0; fc < 3; fc++) {
#pragma unroll
        for (int mt = 0; mt < 3; mt++)
#pragma unroll
            for (int j = 0; j < 4; j++)
#pragma unroll
                for (int reg = 0; reg < 4; reg++)
                    myP[(mt*16 + fq*4 + reg)*72 + j*16 + fr] = (__bf16)S[mt][fc*4 + j][reg];
        // per-wave LDS region; DS ops are in-order per wave -> no barrier needed
#pragma unroll
        for (int kc = 0; kc < 2; kc++) {
            bf16x8 ap[3];
#pragma unroll
            for (int mt = 0; mt < 3; mt++)
                ap[mt] = *(bf16x8*)&myP[(mt*16 + fr)*72 + kc*32 + fq*8];
#pragma unroll
            for (int dt = 0; dt < 4; dt++) {
                bf16x8 b = *(bf16x8*)&Vt[(dt*16 + fr)*200 + fc*64 + kc*32 + fq*8];
#pragma unroll
                for (int mt = 0; mt < 3; mt++)
                    O[mt][dt] = __builtin_amdgcn_mfma_f32_16x16x32_bf16(ap[mt], b, O[mt][dt], 0, 0, 0);
            }
        }
    }
    __bf16* obase = OT + ((size_t)(bn*8 + nh)) * SEQ * 64;
    float cs[4][4], cq[4][4];
#pragma unroll
    for (int r = 0; r < 4; r++)
#pragma unroll
        for (int j = 0; j < 4; j++) { cs[r][j] = 0.f; cq[r][j] = 0.f; }
#pragma unroll
    for (int mt = 0; mt < 3; mt++)
#pragma unroll
        for (int reg = 0; reg < 4; reg++) {
            int e = 48*w + mt*16 + fq*4 + reg;
#pragma unroll
            for (int dt = 0; dt < 4; dt++) {
                __bf16 ob = (__bf16)O[mt][dt][reg];
                obase[(size_t)e*64 + dt*16 + fr] = ob;
                float vf = (float)ob;
                cs[reg][dt] += vf; cq[reg][dt] = fmaf(vf, vf, cq[reg][dt]);
            }
        }
#pragma unroll
    for (int reg = 0; reg < 4; reg++)
#pragma unroll
        for (int dt = 0; dt < 4; dt++) {
            cs[reg][dt] += __shfl_xor(cs[reg][dt], 32);   // fq ^ 2 -> same channel
            cq[reg][dt] += __shfl_xor(cq[reg][dt], 32);
        }
    if (fq < 2) {
#pragma unroll
        for (int reg = 0; reg < 4; reg++)
#pragma unroll
            for (int dt = 0; dt < 4; dt++) {
                int c = ((fq*4 + reg) & 7)*64 + dt*16 + fr;
                atomicAdd(&stLds[c], cs[reg][dt]);
                atomicAdd(&stLds[512 + c], cq[reg][dt]);
            }
    }
    __syncthreads();
#pragma unroll
    for (int j = 0; j < 4; j++)
        atomicAdd(&stg[tid*4 + j], stLds[tid*4 + j]);
}

// ---------------- merged attention dispatch ----------------
// 2048 blocks. Co-resident blocks on one CU are 256 apart in blockIdx (8 XCD x 32 CU
// round-robin); type toggle in bit 8 -> each CU hosts hidden + token blocks.
// BN partial stats fused into epilogues (flat-channel c = (t&7)*64+dloc — the round-3
// failure used nh*64+d; this matches bn_stats1's passing semantics exactly).
__global__ __launch_bounds__(256) void attn_both_k(
    const __bf16* __restrict__ QKb, const __bf16* __restrict__ Vb,
    __bf16* __restrict__ OHb, __bf16* __restrict__ OT, const float* __restrict__ alpha,
    float* __restrict__ st)
{
    __shared__ __bf16 smem[29696];   // 59392 B: phases <=27648 elems + 2048-elem f32 stats scratch
    const int b = blockIdx.x;
    const int type = (b >> 8) & 1;
    const int idx = (b >> 9) * 256 + (b & 255);   // 0..1023 per type
    const int bn = idx >> 3, nh = idx & 7;
    if (type == 0) hidden_attn_body(QKb, Vb, OHb, st + 1024, smem, bn, nh);
    else           token_attn_body(QKb, Vb, OT, alpha, st, smem, bn, nh);
}

// both BN coef sets in one launch: threads 0..511 -> coef0 (g_pre2), 512..1023 -> coef1 (g_pre1)
__global__ void bn_coef_k(const float* __restrict__ st,
                          const float* __restrict__ gA, const float* __restrict__ bA,
                          const float* __restrict__ gB, const float* __restrict__ bB,
                          float* __restrict__ coef)
{
    int tidx = threadIdx.x;            // 1024
    int half = tidx >> 9, c = tidx & 511;
    const float* sb = st + half*1024;
    const float* g = half ? gB : gA;
    const float* b = half ? bB : bA;
    float* co = coef + half*1024;
    float mean = sb[c] * (1.f/24576.f);
    float var  = sb[512+c] * (1.f/24576.f) - mean*mean;
    float sc = rsqrtf(var + EPS) * g[c];
    co[c] = sc;
    co[512 + c] = b[c] - mean * sc;
}

__global__ __launch_bounds__(256) void bn_apply4_k(const float* __restrict__ x, const float* __restrict__ st,
    const float* __restrict__ g, const float* __restrict__ b, float* __restrict__ out)
{
    size_t i = (size_t)blockIdx.x * 256 + threadIdx.x;   // 12288 blocks
    int col4 = i & 127;
    f32x4 v = ((const f32x4*)x)[i];
    f32x4 sm = ((const f32x4*)st)[col4];
    f32x4 sq = ((const f32x4*)(st + 512))[col4];
    f32x4 o;
#pragma unroll
    for (int j = 0; j < 4; j++) {
        int c = col4*4 + j;
        float mean = sm[j] * (1.f/24576.f);
        float var  = sq[j] * (1.f/24576.f) - mean*mean;
        o[j] = (v[j] - mean) * rsqrtf(var + EPS) * g[c] + b[c];
    }
    ((f32x4*)out)[i] = o;
}

extern "C" void kernel_launch(void* const* d_in, const int* in_sizes, int n_in,
                              void* d_out, int out_size, void* d_ws, size_t ws_size,
                              hipStream_t stream)
{
    const float* src    = (const float*)d_in[0];
    const float* qk_w   = (const float*)d_in[1];
    const float* qk_b   = (const float*)d_in[2];
    const float* v_w    = (const float*)d_in[3];
    const float* v_b    = (const float*)d_in[4];
    const float* alpha  = (const float*)d_in[5];
    const float* g_pre1 = (const float*)d_in[6];
    const float* b_pre1 = (const float*)d_in[7];
    const float* g_pre2 = (const float*)d_in[8];
    const float* b_pre2 = (const float*)d_in[9];
    const float* ff1_w1 = (const float*)d_in[10];
    const float* ff1_b1 = (const float*)d_in[11];
    const float* ff1_w2 = (const float*)d_in[12];
    const float* ff1_b2 = (const float*)d_in[13];
    const float* ff2_w1 = (const float*)d_in[14];
    const float* ff2_b1 = (const float*)d_in[15];
    const float* ff2_w2 = (const float*)d_in[16];
    const float* ff2_b2 = (const float*)d_in[17];
    const float* g_attn = (const float*)d_in[18];
    const float* b_attn = (const float*)d_in[19];
    float* out = (float*)d_out;

    // ws layout (bf16 units) — ~187 MB total
    __bf16* wq   = (__bf16*)d_ws;                       //  524288
    __bf16* wv   = wq  + 524288;                        //  262144
    __bf16* w11  = wv  + 262144;                        // 1048576
    __bf16* w12  = w11 + 1048576;                       // 1048576
    __bf16* w21  = w12 + 1048576;                       // 1048576
    __bf16* w22  = w21 + 1048576;                       // 1048576
    __bf16* srcb  = w22 + 1048576;                      // 12582912
    __bf16* srcnb = srcb + (size_t)NTOK*512;            // 12582912
    __bf16* QKb   = srcnb + (size_t)NTOK*512;           // 25165824
    __bf16* Vb    = QKb + (size_t)NTOK*1024;            // 12582912
    __bf16* OHbf  = Vb + (size_t)NTOK*512;              // 12582912
    __bf16* o3bf  = OHbf + (size_t)NTOK*512;            // 12582912
    float*  stats = (float*)(o3bf + (size_t)NTOK*512);  // 3072 f32: [0..1023] o3/token, [1024..2047] OH/hidden, [2048..3071] final
    float*  coef0 = stats + 3072;                       // 2048 f32 (o3 BN then o2 BN)
    float*  bias1p = coef0 + 2048;                      // 2048 f32 (folded FF1 bias)
    float*  bias2p = bias1p + 2048;                     // 2048 f32 (folded FF2 bias)
    // FFN hidden (per 12288-row chunk) overlays the dead srcb..Vb span:
    __bf16* H1 = srcb;                                  // 12288 x 2048
    __bf16* H2 = H1 + (size_t)12288*2048;               // 12288 x 2048
    float *st2 = stats + 2048;

    hipMemsetAsync(stats, 0, 3072*sizeof(float), stream);

    // 0. one-time bf16 conversions + src prep (one dispatch)
    cvtprep_k<<<4864 + NTOK/4, 256, 0, stream>>>(qk_w, v_w, ff1_w1, ff1_w2, ff2_w1, ff2_w2, wq,
                                                 src, srcb, srcnb);

    // 1. both projections in ONE dispatch (n-split): n-tiles 0..7 -> QK proj
    //    (A=srcnb, B=wq, N=1024), n-tiles 8..11 -> V proj (A=srcb, B=wv, N=512).
    gemm_k<false,false,true><<<dim3(12, 192), 256, 0, stream>>>(
        srcnb, wq, QKb, 1024, 512, qk_b,
        srcb,  wv, Vb,  v_b, 1024, 512);

    // 2+3. both attentions in one dispatch; bit-8 type toggle; T14 async V-stage;
    //      batched in-LDS decay scan; BN partial stats fused into epilogues.
    attn_both_k<<<2048, 256, 0, stream>>>(QKb, Vb, OHbf, o3bf, alpha, stats);

    // 4. BN coef from fused stats; BN affine folded into W1 + bias
    bn_coef_k<<<1, 1024, 0, stream>>>(stats, g_pre2, b_pre2, g_pre1, b_pre1, coef0);
    w1scale_k<<<1024, 256, 0, stream>>>(w11, w21, coef0, ff1_b1, ff2_b1, bias1p, bias2p);

    // 5. FFN in 2 chunks of 12288 rows; both FF1 GEMMs fused into one 3072-block
    //    dual-source dispatch (m-split); gemm2 double-buffered (stage-ahead 2-phase).
    for (int ch = 0; ch < 2; ch++) {
        size_t off = (size_t)ch * 12288 * 512;
        gemm_k<true,true,false><<<dim3(16, 192), 256, 0, stream>>>(
            o3bf + off, w11, H1, 2048, 512, bias1p,
            OHbf + off, w21, H2, bias2p, 12288, 2048);
        gemm2_k<<<768, 256, 0, stream>>>(H1, H2, w12, w22, out + off,
                                         ff1_b2, ff2_b2, src + off, st2);
    }

    // 6. final BN (in place on d_out)
    bn_apply4_k<<<12288, 256, 0, stream>>>(out, st2, g_attn, b_attn, out);
}

// Round 10
// 633.790 us; speedup vs baseline: 1.1266x; 1.1266x over previous
//
#include <hip/hip_runtime.h>
#include <math.h>

#define SEQ 192
#define NTOK 24576      // 128*192
#define EPS 1e-5f

typedef __bf16 bf16x8 __attribute__((ext_vector_type(8)));
typedef __bf16 bf16x4 __attribute__((ext_vector_type(4)));
typedef float  f32x4  __attribute__((ext_vector_type(4)));

__device__ __forceinline__ void load_lds16(const __bf16* g, __bf16* l) {
    __builtin_amdgcn_global_load_lds(
        (const __attribute__((address_space(1))) uint32_t*)g,
        (__attribute__((address_space(3))) uint32_t*)l, 16, 0, 0);
}

// tanh-form GELU via sigmoid: x*sigmoid(1.5958*(x+0.044715 x^3))
__device__ __forceinline__ float gelu_f(float x) {
    float z = 1.5957691216057308f * x * fmaf(0.044715f, x*x, 1.f);
    float e = __expf(-z);
    return x * __builtin_amdgcn_rcpf(1.f + e);
}

// ---------------- fused: weight f32->bf16 convert + src prep (one dispatch) ----------------
__global__ __launch_bounds__(256) void cvtprep_k(
    const float* __restrict__ s0, const float* __restrict__ s1, const float* __restrict__ s2,
    const float* __restrict__ s3, const float* __restrict__ s4, const float* __restrict__ s5,
    __bf16* __restrict__ dst,
    const float* __restrict__ src, __bf16* __restrict__ srcb, __bf16* __restrict__ srcnb)
{
    if (blockIdx.x < 4864) {
        int i = blockIdx.x * 256 + threadIdx.x;   // f32x4 units
        int f = i * 4;
        const float* s; int off;
        if      (f <  524288) { s = s0; off = 0;       }
        else if (f <  786432) { s = s1; off = 524288;  }
        else if (f < 1835008) { s = s2; off = 786432;  }
        else if (f < 2883584) { s = s3; off = 1835008; }
        else if (f < 3932160) { s = s4; off = 2883584; }
        else                  { s = s5; off = 3932160; }
        f32x4 v = *(const f32x4*)&s[f - off];
        bf16x4 o;
        o[0]=(__bf16)v[0]; o[1]=(__bf16)v[1]; o[2]=(__bf16)v[2]; o[3]=(__bf16)v[3];
        ((bf16x4*)dst)[i] = o;
    } else {
        int blk = blockIdx.x - 4864;              // 6144 blocks
        int w = threadIdx.x >> 6, lane = threadIdx.x & 63;
        size_t token = blk * 4 + w;
        const float* p = src + token * 512 + lane * 8;
        f32x4 a0 = *(const f32x4*)p;
        f32x4 a1 = *(const f32x4*)(p + 4);
        float s = a0[0]*a0[0]+a0[1]*a0[1]+a0[2]*a0[2]+a0[3]*a0[3]
                + a1[0]*a1[0]+a1[1]*a1[1]+a1[2]*a1[2]+a1[3]*a1[3];
#pragma unroll
        for (int off = 32; off; off >>= 1) s += __shfl_xor(s, off);
        float rs = rsqrtf(s);
        bf16x8 vb, vn;
#pragma unroll
        for (int q = 0; q < 4; q++) {
            vb[q]   = (__bf16)a0[q];      vn[q]   = (__bf16)(a0[q]*rs);
            vb[q+4] = (__bf16)a1[q];      vn[q+4] = (__bf16)(a1[q]*rs);
        }
        *(bf16x8*)&srcb[token*512 + lane*8]  = vb;
        *(bf16x8*)&srcnb[token*512 + lane*8] = vn;
    }
}

// ---------------- bf16 MFMA NT GEMM, BK=64, XOR-swizzled LDS, bf16 out ----------------
// 128x128 tile; m-tiles XCD-grouped.
// DUALM: rows >= M1 come from a second (A,B,C,bias) set (same N).
// NSPLIT: n-tiles >= M1 columns come from a second (A,B,C,bias) set with width N2.
template<bool GELU, bool DUALM, bool NSPLIT>
__global__ __launch_bounds__(256) void gemm_k(
    const __bf16* __restrict__ A, const __bf16* __restrict__ B, __bf16* __restrict__ C,
    int N, int K, const float* __restrict__ bias,
    const __bf16* __restrict__ A2, const __bf16* __restrict__ B2, __bf16* __restrict__ C2,
    const float* __restrict__ bias2, int M1, int N2)
{
    __shared__ __bf16 As[8192];   // [128][64], seg XOR-swizzled
    __shared__ __bf16 Bs[8192];
    const int tid = threadIdx.x, lane = tid & 63, w = tid >> 6;
    const int wr = w >> 1, wc = w & 1;
    const int b = blockIdx.y * gridDim.x + blockIdx.x;
    const int xcd = b & 7, bi = b >> 3;
    const int ypx = gridDim.y >> 3;
    int m0 = (xcd * ypx + bi / gridDim.x) * 128;
    int n0 = (bi % gridDim.x) * 128;
    if (DUALM && m0 >= M1)  { A = A2; B = B2; C = C2; bias = bias2; m0 -= M1; }
    if (NSPLIT && n0 >= M1) { A = A2; B = B2; C = C2; bias = bias2; n0 -= M1; N = N2; }
    const int fr = lane & 15, fq = lane >> 4;
    const int grow = 8*w + (lane >> 3);
    const int gcol = ((lane & 7) ^ (lane >> 3)) * 8;
    const __bf16* gB = B + (size_t)(n0 + grow) * K + gcol;
    const __bf16* gA = A + (size_t)(m0 + grow) * K + gcol;
    __bf16* ldsA = As + 8*w*64 + lane*8;
    __bf16* ldsB = Bs + 8*w*64 + lane*8;

    f32x4 acc[4][4];
#pragma unroll
    for (int i = 0; i < 4; i++)
#pragma unroll
        for (int j = 0; j < 4; j++) acc[i][j] = (f32x4){0.f,0.f,0.f,0.f};

    for (int k0 = 0; k0 < K; k0 += 64) {
#pragma unroll
        for (int i = 0; i < 4; i++)
            load_lds16(gA + k0 + (size_t)(32*i)*K, ldsA + i*2048);
#pragma unroll
        for (int i = 0; i < 4; i++)
            load_lds16(gB + k0 + (size_t)(32*i)*K, ldsB + i*2048);
        __syncthreads();
#pragma unroll
        for (int kk = 0; kk < 2; kk++) {
            bf16x8 af[4], bfv[4];
#pragma unroll
            for (int i = 0; i < 4; i++)
                af[i] = *(bf16x8*)&As[(wr*64 + i*16 + fr)*64 + (((kk*4+fq) ^ (fr&7))*8)];
#pragma unroll
            for (int j = 0; j < 4; j++)
                bfv[j] = *(bf16x8*)&Bs[(wc*64 + j*16 + fr)*64 + (((kk*4+fq) ^ (fr&7))*8)];
#pragma unroll
            for (int i = 0; i < 4; i++)
#pragma unroll
                for (int j = 0; j < 4; j++)
                    acc[i][j] = __builtin_amdgcn_mfma_f32_16x16x32_bf16(af[i], bfv[j], acc[i][j], 0, 0, 0);
        }
        __syncthreads();
    }
    const int r4 = lane >> 4, cc = lane & 15;
#pragma unroll
    for (int i = 0; i < 4; i++) {
#pragma unroll
        for (int r = 0; r < 4; r++) {
            int m = m0 + wr*64 + i*16 + r4*4 + r;
#pragma unroll
            for (int j = 0; j < 4; j++) {
                int n = n0 + wc*64 + j*16 + cc;
                float v = acc[i][j][r] + bias[n];
                if (GELU) v = gelu_f(v);
                C[(size_t)m * N + n] = (__bf16)v;
            }
        }
    }
}

// ---------------- fold BN affine into W1 (both FFNs in one dispatch) ----------------
__global__ __launch_bounds__(256) void w1scale_k(
    __bf16* __restrict__ w1a, __bf16* __restrict__ w1b, const float* __restrict__ coef01,
    const float* __restrict__ b1in, const float* __restrict__ b2in,
    float* __restrict__ b1out, float* __restrict__ b2out)
{
    const int half = blockIdx.x >> 9;
    __bf16* wbase = half ? w1b : w1a;
    const float* coef = coef01 + half*1024;
    const float* bin  = half ? b2in  : b1in;
    float* bout       = half ? b2out : b1out;
    const int wv = threadIdx.x >> 6, lane = threadIdx.x & 63;
    const int n = (blockIdx.x & 511) * 4 + wv;
    __bf16* p = wbase + (size_t)n * 512 + lane * 8;
    bf16x8 v = *(bf16x8*)p;
    f32x4 sc0 = *(const f32x4*)(coef + lane*8);
    f32x4 sc1 = *(const f32x4*)(coef + lane*8 + 4);
    f32x4 sh0 = *(const f32x4*)(coef + 512 + lane*8);
    f32x4 sh1 = *(const f32x4*)(coef + 512 + lane*8 + 4);
    float dot = 0.f;
    bf16x8 o;
#pragma unroll
    for (int q = 0; q < 4; q++) {
        float w0 = (float)v[q], w1 = (float)v[q+4];
        o[q]   = (__bf16)(w0 * sc0[q]);
        o[q+4] = (__bf16)(w1 * sc1[q]);
        dot = fmaf(w0, sh0[q], dot);
        dot = fmaf(w1, sh1[q], dot);
    }
    *(bf16x8*)p = o;
#pragma unroll
    for (int off = 32; off; off >>= 1) dot += __shfl_xor(dot, off);
    if (lane == 0) bout[n] = bin[n] + dot;
}

// ---------------- dual-source W2 GEMM, double-buffered (stage-ahead 2-phase) ----------------
// out = H1*B1^T + H2*B2^T + b1 + b2 + resid ; 64x128 tile, 768 blocks, XCD-grouped.
__global__ __launch_bounds__(256) void gemm2_k(
    const __bf16* __restrict__ A1, const __bf16* __restrict__ A2,
    const __bf16* __restrict__ B1, const __bf16* __restrict__ B2,
    float* __restrict__ C, const float* __restrict__ b1, const float* __restrict__ b2,
    const float* __restrict__ resid, float* __restrict__ st)
{
    __shared__ __bf16 As[2][4096];   // 64 x 64 x 2buf
    __shared__ __bf16 Bs[2][8192];   // 128 x 64 x 2buf
    const int tid = threadIdx.x, lane = tid & 63, w = tid >> 6;
    const int wr = w >> 1, wc = w & 1;
    const int vb = blockIdx.x;                  // 768 = 8 xcd * 24 m * 4 n
    const int xcd = vb & 7, k2 = vb >> 3;
    const int m0 = (xcd*24 + (k2 >> 2)) * 64;
    const int n0 = (k2 & 3) * 128;
    const int fr = lane & 15, fq = lane >> 4;
    const int grow = 8*w + (lane >> 3);
    const int gcol = ((lane & 7) ^ (lane >> 3)) * 8;
    const int K = 2048;
    const int ldsoff = 8*w*64 + lane*8;
    const __bf16* gA1 = A1 + (size_t)(m0 + grow) * K + gcol;
    const __bf16* gA2 = A2 + (size_t)(m0 + grow) * K + gcol;
    const __bf16* gB1 = B1 + (size_t)(n0 + grow) * K + gcol;
    const __bf16* gB2 = B2 + (size_t)(n0 + grow) * K + gcol;

#define G2_STAGE(pb, it_) do {                                              \
        int half_ = (it_) >> 5, k0_ = ((it_) & 31) * 64;                    \
        const __bf16* ga_ = (half_ ? gA2 : gA1) + k0_;                      \
        const __bf16* gb_ = (half_ ? gB2 : gB1) + k0_;                      \
        load_lds16(ga_,                  &As[pb][ldsoff]);                  \
        load_lds16(ga_ + (size_t)32*K,   &As[pb][ldsoff + 2048]);           \
        load_lds16(gb_,                  &Bs[pb][ldsoff]);                  \
        load_lds16(gb_ + (size_t)32*K,   &Bs[pb][ldsoff + 2048]);           \
        load_lds16(gb_ + (size_t)64*K,   &Bs[pb][ldsoff + 4096]);           \
        load_lds16(gb_ + (size_t)96*K,   &Bs[pb][ldsoff + 6144]);           \
    } while (0)

    f32x4 acc[2][4];
#pragma unroll
    for (int i = 0; i < 2; i++)
#pragma unroll
        for (int j = 0; j < 4; j++) acc[i][j] = (f32x4){0.f,0.f,0.f,0.f};

    G2_STAGE(0, 0);
    asm volatile("s_waitcnt vmcnt(0)" ::: "memory");
    __syncthreads();
    for (int it = 0; it < 64; ++it) {
        const int cur = it & 1;
        if (it + 1 < 64) G2_STAGE(cur ^ 1, it + 1);   // loads for next tile fly over compute
#pragma unroll
        for (int kk = 0; kk < 2; kk++) {
            bf16x8 af[2], bfv[4];
#pragma unroll
            for (int i = 0; i < 2; i++)
                af[i] = *(bf16x8*)&As[cur][(wr*32 + i*16 + fr)*64 + (((kk*4+fq) ^ (fr&7))*8)];
#pragma unroll
            for (int j = 0; j < 4; j++)
                bfv[j] = *(bf16x8*)&Bs[cur][(wc*64 + j*16 + fr)*64 + (((kk*4+fq) ^ (fr&7))*8)];
#pragma unroll
            for (int i = 0; i < 2; i++)
#pragma unroll
                for (int j = 0; j < 4; j++)
                    acc[i][j] = __builtin_amdgcn_mfma_f32_16x16x32_bf16(af[i], bfv[j], acc[i][j], 0, 0, 0);
        }
        asm volatile("s_waitcnt vmcnt(0)" ::: "memory");
        __syncthreads();
    }
#undef G2_STAGE

    const int r4 = lane >> 4, cc = lane & 15;
    float cs[4] = {0,0,0,0}, cq[4] = {0,0,0,0};
#pragma unroll
    for (int i = 0; i < 2; i++) {
#pragma unroll
        for (int r = 0; r < 4; r++) {
            int m = m0 + wr*32 + i*16 + r4*4 + r;
#pragma unroll
            for (int j = 0; j < 4; j++) {
                int n = n0 + wc*64 + j*16 + cc;
                size_t idx = (size_t)m * 512 + n;
                float v = acc[i][j][r] + b1[n] + b2[n] + resid[idx];
                C[idx] = v;
                cs[j] += v; cq[j] = fmaf(v, v, cq[j]);
            }
        }
    }
#pragma unroll
    for (int j = 0; j < 4; j++) {
        cs[j] += __shfl_xor(cs[j], 16); cs[j] += __shfl_xor(cs[j], 32);
        cq[j] += __shfl_xor(cq[j], 16); cq[j] += __shfl_xor(cq[j], 32);
    }
    if (r4 == 0) {
#pragma unroll
        for (int j = 0; j < 4; j++) {
            int n = n0 + wc*64 + j*16 + cc;
            atomicAdd(&st[n], cs[j]);
            atomicAdd(&st[512 + n], cq[j]);
        }
    }
}

// ---------------- hidden-axis attention body (T14: V loads issued early) ----------------
__device__ __forceinline__ void hidden_attn_body(
    const __bf16* __restrict__ QKb, const __bf16* __restrict__ Vb, __bf16* __restrict__ OHb,
    __bf16* smem, int bn, int nh)
{
    __bf16* Qt = smem;             // 64 x 200 (phase 1)  [e][t]
    __bf16* Kt = smem + 12800;     // 64 x 200            [f][t]
    __bf16* Ps = smem;             // 64 x 72  (phase 2)  [e][f]
    __bf16* Vs = smem + 4608;      // 192 x 72            [t][f]
    const int tid = threadIdx.x, lane = tid & 63, w = tid >> 6;
    const int fr = lane & 15, fq = lane >> 4;
    const size_t rowbase = (size_t)bn * SEQ;

    // transpose-stage q^T,k^T: per task one column-of-8 (8 coalesced reads + 1 b128 write)
#pragma unroll
    for (int it = 0; it < 12; it++) {
        int tk = tid + (it % 6) * 256;          // 0..1535
        int j = tk & 63, tg = tk >> 6;          // tg 0..23
        const __bf16* gsrc = QKb + (rowbase + tg*8)*1024 + nh*64 + j + (it >= 6 ? 512 : 0);
        bf16x8 v;
#pragma unroll
        for (int u = 0; u < 8; u++) v[u] = gsrc[(size_t)u*1024];
        __bf16* dst = (it >= 6 ? Kt : Qt) + j*200 + tg*8;
        *(bf16x8*)dst = v;
    }
    // T14 async-STAGE: issue V loads NOW (land under QK^T+softmax); write to LDS late.
    bf16x8 vreg[6];
#pragma unroll
    for (int it = 0; it < 6; it++) {
        int i = tid + it*256;
        int t = i >> 3, s = i & 7;
        vreg[it] = *(const bf16x8*)&Vb[(rowbase+t)*512 + nh*64 + s*8];
    }
    __syncthreads();

    f32x4 acc[4];
#pragma unroll
    for (int i = 0; i < 4; i++) acc[i] = (f32x4){0.f,0.f,0.f,0.f};
#pragma unroll
    for (int kc = 0; kc < 6; kc++) {
        bf16x8 a = *(bf16x8*)&Qt[(w*16 + fr)*200 + kc*32 + fq*8];
#pragma unroll
        for (int nt = 0; nt < 4; nt++) {
            bf16x8 b = *(bf16x8*)&Kt[(nt*16 + fr)*200 + kc*32 + fq*8];
            acc[nt] = __builtin_amdgcn_mfma_f32_16x16x32_bf16(a, b, acc[nt], 0, 0, 0);
        }
    }
    const float sc = 13.856406460551018f;   // sqrt(192)
    float pn[4][4];
#pragma unroll
    for (int reg = 0; reg < 4; reg++) {
        float m = -1e30f;
#pragma unroll
        for (int nt = 0; nt < 4; nt++) { acc[nt][reg] *= sc; m = fmaxf(m, acc[nt][reg]); }
#pragma unroll
        for (int off = 1; off < 16; off <<= 1) m = fmaxf(m, __shfl_xor(m, off));
        float l = 0.f;
#pragma unroll
        for (int nt = 0; nt < 4; nt++) { pn[nt][reg] = __expf(acc[nt][reg] - m); l += pn[nt][reg]; }
#pragma unroll
        for (int off = 1; off < 16; off <<= 1) l += __shfl_xor(l, off);
        float inv = 1.f / l;
#pragma unroll
        for (int nt = 0; nt < 4; nt++) pn[nt][reg] *= inv;
    }
    __syncthreads();                                   // Qt/Kt dead
#pragma unroll
    for (int nt = 0; nt < 4; nt++)
#pragma unroll
        for (int reg = 0; reg < 4; reg++)
            Ps[(w*16 + fq*4 + reg)*72 + nt*16 + fr] = (__bf16)pn[nt][reg];
#pragma unroll
    for (int it = 0; it < 6; it++) {                   // V regs -> LDS (loads long landed)
        int i = tid + it*256;
        int t = i >> 3, s = i & 7;
        *(bf16x8*)&Vs[t*72 + s*8] = vreg[it];
    }
    __syncthreads();

    f32x4 o[3][4];
#pragma unroll
    for (int i = 0; i < 3; i++)
#pragma unroll
        for (int j = 0; j < 4; j++) o[i][j] = (f32x4){0.f,0.f,0.f,0.f};
#pragma unroll
    for (int kc = 0; kc < 2; kc++) {
        bf16x8 av[3];
#pragma unroll
        for (int mt = 0; mt < 3; mt++)
            av[mt] = *(bf16x8*)&Vs[(48*w + mt*16 + fr)*72 + kc*32 + fq*8];
#pragma unroll
        for (int nt = 0; nt < 4; nt++) {
            bf16x8 b = *(bf16x8*)&Ps[(nt*16 + fr)*72 + kc*32 + fq*8];
#pragma unroll
            for (int mt = 0; mt < 3; mt++)
                o[mt][nt] = __builtin_amdgcn_mfma_f32_16x16x32_bf16(av[mt], b, o[mt][nt], 0, 0, 0);
        }
    }
    __bf16* obase = OHb + ((size_t)(bn*8 + nh)) * SEQ * 64;
#pragma unroll
    for (int mt = 0; mt < 3; mt++)
#pragma unroll
        for (int reg = 0; reg < 4; reg++) {
            int t = 48*w + mt*16 + fq*4 + reg;
#pragma unroll
            for (int nt = 0; nt < 4; nt++)
                obase[(size_t)t*64 + nt*16 + fr] = (__bf16)o[mt][nt][reg];
        }
}

// ---------------- token-axis attention body (batched in-LDS decay scan; T14 V^T gather early) --
__device__ __forceinline__ void token_attn_body(
    const __bf16* __restrict__ QKb, const __bf16* __restrict__ Vb, __bf16* __restrict__ OT,
    const float* __restrict__ alpha, __bf16* smem, int bn, int nh)
{
    __bf16* Qs = smem;              // 192 x 72 (phase A) [e][d]
    __bf16* Ks = smem + 13824;      // 192 x 72           [f][d]
    __bf16* Vt = smem;              // 64 x 200 (phase B) [d][f]
    __bf16* Pw = smem + 12800;      // 4 waves x (48 x 72)
    const int tid = threadIdx.x, lane = tid & 63, w = tid >> 6;
    const int fr = lane & 15, fq = lane >> 4;
    const size_t rowbase = (size_t)bn * SEQ;

    for (int i = tid; i < 1536; i += 256) {
        int t = i >> 3, s = i & 7;
        const __bf16* g = QKb + (rowbase + t)*1024 + nh*64;
        *(bf16x8*)&Qs[t*72 + s*8] = *(const bf16x8*)&g[s*8];
        *(bf16x8*)&Ks[t*72 + s*8] = *(const bf16x8*)&g[512 + s*8];
    }
    // T14 async-STAGE: issue the V^T transpose-gather NOW (48 strided 2B loads/thread,
    // L2/L3 latency) — lands under scan + QK^T + softmax; LDS write happens in phase B.
    bf16x8 vreg[6];
#pragma unroll
    for (int it = 0; it < 6; it++) {
        int tk = tid + it * 256;                // 0..1535
        int d = tk & 63, tg = tk >> 6;
        const __bf16* gsrc = Vb + (rowbase + tg*8)*512 + nh*64 + d;
#pragma unroll
        for (int u = 0; u < 8; u++) vreg[it][u] = gsrc[(size_t)u*512];
    }
    __syncthreads();

    // in-LDS decay scan over t, 16-wide batched: 16 reads issued together so the
    // ~LDS-read latency overlaps 16-deep. Per-element arithmetic order is identical
    // to the scalar loop (round-9 pass confirmed numerics; only the global-atomic
    // stats fusion of that round regressed and is removed here).
    if (tid < 128) {
        const int d = tid & 63;
        __bf16* col = (tid < 64) ? (Qs + d) : (Ks + d);
        const float av = 1.f / (1.f + __expf(-alpha[d]));
        const float r = 1.f - av;
        float P = 0.f, pw = 1.f;
        for (int t0 = 0; t0 < SEQ; t0 += 16) {
            float x[16];
#pragma unroll
            for (int u = 0; u < 16; u++) x[u] = (float)col[(t0+u)*72];
#pragma unroll
            for (int u = 0; u < 16; u++) { P = fmaf(pw, x[u], P); x[u] = P; pw *= r; }
#pragma unroll
            for (int u = 0; u < 16; u++) col[(t0+u)*72] = (__bf16)x[u];
        }
        float f = av;
        for (int t0 = SEQ-16; t0 >= 0; t0 -= 16) {
            float x[16];
#pragma unroll
            for (int u = 0; u < 16; u++) x[u] = (float)col[(t0+u)*72];
#pragma unroll
            for (int u = 15; u >= 0; u--) { x[u] *= f; f *= r; }
#pragma unroll
            for (int u = 0; u < 16; u++) col[(t0+u)*72] = (__bf16)x[u];
        }
    }
    __syncthreads();

    f32x4 S[3][12];
#pragma unroll
    for (int i = 0; i < 3; i++)
#pragma unroll
        for (int j = 0; j < 12; j++) S[i][j] = (f32x4){0.f,0.f,0.f,0.f};
#pragma unroll
    for (int kc = 0; kc < 2; kc++) {
        bf16x8 aq[3];
#pragma unroll
        for (int mt = 0; mt < 3; mt++)
            aq[mt] = *(bf16x8*)&Qs[(48*w + mt*16 + fr)*72 + kc*32 + fq*8];
#pragma unroll
        for (int nt = 0; nt < 12; nt++) {
            bf16x8 b = *(bf16x8*)&Ks[(nt*16 + fr)*72 + kc*32 + fq*8];
#pragma unroll
            for (int mt = 0; mt < 3; mt++)
                S[mt][nt] = __builtin_amdgcn_mfma_f32_16x16x32_bf16(aq[mt], b, S[mt][nt], 0, 0, 0);
        }
    }
#pragma unroll
    for (int mt = 0; mt < 3; mt++)
#pragma unroll
        for (int reg = 0; reg < 4; reg++) {
            float m = -1e30f;
#pragma unroll
            for (int nt = 0; nt < 12; nt++) { S[mt][nt][reg] *= 8.f; m = fmaxf(m, S[mt][nt][reg]); }
#pragma unroll
            for (int off = 1; off < 16; off <<= 1) m = fmaxf(m, __shfl_xor(m, off));
            float l = 0.f;
#pragma unroll
            for (int nt = 0; nt < 12; nt++) { S[mt][nt][reg] = __expf(S[mt][nt][reg] - m); l += S[mt][nt][reg]; }
#pragma unroll
            for (int off = 1; off < 16; off <<= 1) l += __shfl_xor(l, off);
            float inv = 1.f / l;
#pragma unroll
            for (int nt = 0; nt < 12; nt++) S[mt][nt][reg] *= inv;
        }
    __syncthreads();                                   // Qs/Ks dead
    // V^T regs -> LDS (gather loads issued in phase A have long landed)
#pragma unroll
    for (int it = 0; it < 6; it++) {
        int tk = tid + it * 256;
        int d = tk & 63, tg = tk >> 6;
        *(bf16x8*)&Vt[d*200 + tg*8] = vreg[it];
    }
    __syncthreads();

    f32x4 O[3][4];
#pragma unroll
    for (int i = 0; i < 3; i++)
#pragma unroll
        for (int j = 0; j < 4; j++) O[i][j] = (f32x4){0.f,0.f,0.f,0.f};
    __bf16* myP = Pw + w*3456;
#pragma unroll
    for (int fc = 0; fc < 3; fc++) {
#pragma unroll
        for (int mt = 0; mt < 3; mt++)
#pragma unroll
            for (int j = 0; j < 4; j++)
#pragma unroll
                for (int reg = 0; reg < 4; reg++)
                    myP[(mt*16 + fq*4 + reg)*72 + j*16 + fr] = (__bf16)S[mt][fc*4 + j][reg];
        // per-wave LDS region; DS ops are in-order per wave -> no barrier needed
#pragma unroll
        for (int kc = 0; kc < 2; kc++) {
            bf16x8 ap[3];
#pragma unroll
            for (int mt = 0; mt < 3; mt++)
                ap[mt] = *(bf16x8*)&myP[(mt*16 + fr)*72 + kc*32 + fq*8];
#pragma unroll
            for (int dt = 0; dt < 4; dt++) {
                bf16x8 b = *(bf16x8*)&Vt[(dt*16 + fr)*200 + fc*64 + kc*32 + fq*8];
#pragma unroll
                for (int mt = 0; mt < 3; mt++)
                    O[mt][dt] = __builtin_amdgcn_mfma_f32_16x16x32_bf16(ap[mt], b, O[mt][dt], 0, 0, 0);
            }
        }
    }
    __bf16* obase = OT + ((size_t)(bn*8 + nh)) * SEQ * 64;
#pragma unroll
    for (int mt = 0; mt < 3; mt++)
#pragma unroll
        for (int reg = 0; reg < 4; reg++) {
            int e = 48*w + mt*16 + fq*4 + reg;
#pragma unroll
            for (int dt = 0; dt < 4; dt++)
                obase[(size_t)e*64 + dt*16 + fr] = (__bf16)O[mt][dt][reg];
        }
}

// ---------------- merged attention dispatch ----------------
// 2048 blocks. Co-resident blocks on one CU are 256 apart in blockIdx (8 XCD x 32 CU
// round-robin), so the type toggle lives in bit 8: block b and b+256 have opposite
// types -> each CU hosts one hidden + one token block (heterogeneous phase overlap).
// Stats fusion removed (r9: 2.1M contended global atomics doubled the kernel; WRITE
// +32MB). Two-stage bn_stats restored — it is traffic-roofline-bound at ~14 us.
__global__ __launch_bounds__(256) void attn_both_k(
    const __bf16* __restrict__ QKb, const __bf16* __restrict__ Vb,
    __bf16* __restrict__ OHb, __bf16* __restrict__ OT, const float* __restrict__ alpha)
{
    __shared__ __bf16 smem[27648];
    const int b = blockIdx.x;
    const int type = (b >> 8) & 1;
    const int idx = (b >> 9) * 256 + (b & 255);   // 0..1023 per type
    const int bn = idx >> 3, nh = idx & 7;
    if (type == 0) hidden_attn_body(QKb, Vb, OHb, smem, bn, nh);
    else           token_attn_body(QKb, Vb, OT, alpha, smem, bn, nh);
}

// ---------------- BatchNorm stats, two-stage, both tensors in one dispatch ----------------
__global__ __launch_bounds__(256) void bn_stats1_k(const __bf16* __restrict__ x0,
    const __bf16* __restrict__ x1, float* __restrict__ part)
{
    __shared__ float red[3072];            // 3 rowlanes x (512 sum + 512 sq)
    const __bf16* x = (blockIdx.x < 256) ? x0 : x1;
    const int blk = blockIdx.x & 255;
    const int col8 = threadIdx.x & 63;     // 8 channels per thread
    const int rl   = threadIdx.x >> 6;     // 0..3
    const size_t r0 = (size_t)blk * 96;
    f32x4 sA = {0,0,0,0}, sB = {0,0,0,0}, qA = {0,0,0,0}, qB = {0,0,0,0};
    for (int r = rl; r < 96; r += 4) {
        bf16x8 v = *(const bf16x8*)&x[(r0 + r)*512 + col8*8];
        f32x4 lo = { (float)v[0], (float)v[1], (float)v[2], (float)v[3] };
        f32x4 hi = { (float)v[4], (float)v[5], (float)v[6], (float)v[7] };
        sA += lo; sB += hi;
        qA += lo*lo; qB += hi*hi;
    }
    if (rl > 0) {
        float* p = &red[(rl-1)*1024];
        *(f32x4*)&p[col8*8]       = sA;  *(f32x4*)&p[col8*8 + 4]       = sB;
        *(f32x4*)&p[512 + col8*8] = qA;  *(f32x4*)&p[512 + col8*8 + 4] = qB;
    }
    __syncthreads();
    if (rl == 0) {
#pragma unroll
        for (int k = 0; k < 3; k++) {
            float* p = &red[k*1024];
            sA += *(f32x4*)&p[col8*8];       sB += *(f32x4*)&p[col8*8 + 4];
            qA += *(f32x4*)&p[512 + col8*8]; qB += *(f32x4*)&p[512 + col8*8 + 4];
        }
        float* o = &part[(size_t)blockIdx.x * 1024];
        *(f32x4*)&o[col8*8]       = sA;  *(f32x4*)&o[col8*8 + 4]       = sB;
        *(f32x4*)&o[512 + col8*8] = qA;  *(f32x4*)&o[512 + col8*8 + 4] = qB;
    }
}

__global__ __launch_bounds__(256) void bn_stats2_k(const float* __restrict__ part, float* __restrict__ st)
{
    int c = blockIdx.x * 256 + threadIdx.x;   // grid 8 -> 2048 (two tensors)
    int half = c >> 10, cc = c & 1023;
    const float* p = part + (size_t)half * 262144;
    float s0 = 0.f, s1 = 0.f, s2 = 0.f, s3 = 0.f;
    for (int b = 0; b < 256; b += 4) {
        s0 += p[(size_t)b*1024 + cc];
        s1 += p[(size_t)(b+1)*1024 + cc];
        s2 += p[(size_t)(b+2)*1024 + cc];
        s3 += p[(size_t)(b+3)*1024 + cc];
    }
    st[c] = (s0 + s1) + (s2 + s3);
}

// both BN coef sets in one launch: threads 0..511 -> coef0 (g_pre2), 512..1023 -> coef1 (g_pre1)
__global__ void bn_coef_k(const float* __restrict__ st,
                          const float* __restrict__ gA, const float* __restrict__ bA,
                          const float* __restrict__ gB, const float* __restrict__ bB,
                          float* __restrict__ coef)
{
    int tidx = threadIdx.x;            // 1024
    int half = tidx >> 9, c = tidx & 511;
    const float* sb = st + half*1024;
    const float* g = half ? gB : gA;
    const float* b = half ? bB : bA;
    float* co = coef + half*1024;
    float mean = sb[c] * (1.f/24576.f);
    float var  = sb[512+c] * (1.f/24576.f) - mean*mean;
    float sc = rsqrtf(var + EPS) * g[c];
    co[c] = sc;
    co[512 + c] = b[c] - mean * sc;
}

__global__ __launch_bounds__(256) void bn_apply4_k(const float* __restrict__ x, const float* __restrict__ st,
    const float* __restrict__ g, const float* __restrict__ b, float* __restrict__ out)
{
    size_t i = (size_t)blockIdx.x * 256 + threadIdx.x;   // 12288 blocks
    int col4 = i & 127;
    f32x4 v = ((const f32x4*)x)[i];
    f32x4 sm = ((const f32x4*)st)[col4];
    f32x4 sq = ((const f32x4*)(st + 512))[col4];
    f32x4 o;
#pragma unroll
    for (int j = 0; j < 4; j++) {
        int c = col4*4 + j;
        float mean = sm[j] * (1.f/24576.f);
        float var  = sq[j] * (1.f/24576.f) - mean*mean;
        o[j] = (v[j] - mean) * rsqrtf(var + EPS) * g[c] + b[c];
    }
    ((f32x4*)out)[i] = o;
}

extern "C" void kernel_launch(void* const* d_in, const int* in_sizes, int n_in,
                              void* d_out, int out_size, void* d_ws, size_t ws_size,
                              hipStream_t stream)
{
    const float* src    = (const float*)d_in[0];
    const float* qk_w   = (const float*)d_in[1];
    const float* qk_b   = (const float*)d_in[2];
    const float* v_w    = (const float*)d_in[3];
    const float* v_b    = (const float*)d_in[4];
    const float* alpha  = (const float*)d_in[5];
    const float* g_pre1 = (const float*)d_in[6];
    const float* b_pre1 = (const float*)d_in[7];
    const float* g_pre2 = (const float*)d_in[8];
    const float* b_pre2 = (const float*)d_in[9];
    const float* ff1_w1 = (const float*)d_in[10];
    const float* ff1_b1 = (const float*)d_in[11];
    const float* ff1_w2 = (const float*)d_in[12];
    const float* ff1_b2 = (const float*)d_in[13];
    const float* ff2_w1 = (const float*)d_in[14];
    const float* ff2_b1 = (const float*)d_in[15];
    const float* ff2_w2 = (const float*)d_in[16];
    const float* ff2_b2 = (const float*)d_in[17];
    const float* g_attn = (const float*)d_in[18];
    const float* b_attn = (const float*)d_in[19];
    float* out = (float*)d_out;

    // ws layout (bf16 units) — ~187 MB total
    __bf16* wq   = (__bf16*)d_ws;                       //  524288
    __bf16* wv   = wq  + 524288;                        //  262144
    __bf16* w11  = wv  + 262144;                        // 1048576
    __bf16* w12  = w11 + 1048576;                       // 1048576
    __bf16* w21  = w12 + 1048576;                       // 1048576
    __bf16* w22  = w21 + 1048576;                       // 1048576
    __bf16* srcb  = w22 + 1048576;                      // 12582912
    __bf16* srcnb = srcb + (size_t)NTOK*512;            // 12582912
    __bf16* QKb   = srcnb + (size_t)NTOK*512;           // 25165824
    __bf16* Vb    = QKb + (size_t)NTOK*1024;            // 12582912
    __bf16* OHbf  = Vb + (size_t)NTOK*512;              // 12582912
    __bf16* o3bf  = OHbf + (size_t)NTOK*512;            // 12582912
    float*  stats = (float*)(o3bf + (size_t)NTOK*512);  // 3072 f32
    float*  coef0 = stats + 3072;                       // 2048 f32 (o3 BN then o2 BN)
    float*  part0 = coef0 + 2048;                       // 2*262144 f32 (2 MB, contiguous)
    float*  bias1p = part0 + 2*262144;                  // 2048 f32 (folded FF1 bias)
    float*  bias2p = bias1p + 2048;                     // 2048 f32 (folded FF2 bias)
    // FFN hidden (per 12288-row chunk) overlays the dead srcb..Vb span:
    __bf16* H1 = srcb;                                  // 12288 x 2048
    __bf16* H2 = H1 + (size_t)12288*2048;               // 12288 x 2048
    float *st2 = stats + 2048;

    hipMemsetAsync(st2, 0, 1024*sizeof(float), stream);

    // 0. one-time bf16 conversions + src prep (one dispatch)
    cvtprep_k<<<4864 + NTOK/4, 256, 0, stream>>>(qk_w, v_w, ff1_w1, ff1_w2, ff2_w1, ff2_w2, wq,
                                                 src, srcb, srcnb);

    // 1. both projections in ONE dispatch (n-split): n-tiles 0..7 -> QK proj
    //    (A=srcnb, B=wq, N=1024), n-tiles 8..11 -> V proj (A=srcb, B=wv, N=512).
    gemm_k<false,false,true><<<dim3(12, 192), 256, 0, stream>>>(
        srcnb, wq, QKb, 1024, 512, qk_b,
        srcb,  wv, Vb,  v_b, 1024, 512);

    // 2+3. both attentions in one dispatch; bit-8 type toggle; T14 async V-stage;
    //      batched in-LDS decay scan (sole change vs the 642-us round-8 baseline).
    attn_both_k<<<2048, 256, 0, stream>>>(QKb, Vb, OHbf, o3bf, alpha);

    // 4. BN stats (two-stage, flat-channel semantics = reference's reshape);
    //    BN affine folded into W1 + bias
    bn_stats1_k<<<512, 256, 0, stream>>>(o3bf, OHbf, part0);
    bn_stats2_k<<<8, 256, 0, stream>>>(part0, stats);
    bn_coef_k<<<1, 1024, 0, stream>>>(stats, g_pre2, b_pre2, g_pre1, b_pre1, coef0);
    w1scale_k<<<1024, 256, 0, stream>>>(w11, w21, coef0, ff1_b1, ff2_b1, bias1p, bias2p);

    // 5. FFN in 2 chunks of 12288 rows; both FF1 GEMMs fused into one 3072-block
    //    dual-source dispatch (m-split); gemm2 double-buffered (stage-ahead 2-phase).
    for (int ch = 0; ch < 2; ch++) {
        size_t off = (size_t)ch * 12288 * 512;
        gemm_k<true,true,false><<<dim3(16, 192), 256, 0, stream>>>(
            o3bf + off, w11, H1, 2048, 512, bias1p,
            OHbf + off, w21, H2, bias2p, 12288, 2048);
        gemm2_k<<<768, 256, 0, stream>>>(H1, H2, w12, w22, out + off,
                                         ff1_b2, ff2_b2, src + off, st2);
    }

    // 6. final BN (in place on d_out)
    bn_apply4_k<<<12288, 256, 0, stream>>>(out, st2, g_attn, b_attn, out);
}